// Round 1
// baseline (4424.112 us; speedup 1.0000x reference)
//
#include <hip/hip_runtime.h>
#include <cmath>

// Shapes: B=128, D=192, DEPTH=12, H=3(hd=64), E=4, N=65(tokens), NC=100, WIN_HALF=3
// rows = B*N = 8320

#define ROWS 8320
#define DD   192

__device__ __forceinline__ float gelu_f(float x) {
    return 0.5f * x * (1.0f + erff(x * 0.70710678118654752440f));
}

// block-wide sum for blockDim.x == 192; sbuf must be __shared__ float[192]
__device__ __forceinline__ float blk_sum_192(float v, float* sbuf) {
    int tid = threadIdx.x;
    sbuf[tid] = v;
    __syncthreads();
    for (int off = 96; off >= 3; off >>= 1) {
        if (tid < off) sbuf[tid] += sbuf[tid + off];
        __syncthreads();
    }
    float r = sbuf[0] + sbuf[1] + sbuf[2];
    __syncthreads();
    return r;
}

// ---------------- patch embed + LN + cls + pos ----------------
// grid = B*65 blocks, 192 threads
__global__ __launch_bounds__(192) void embed_kernel(
    const float* __restrict__ x, const float* __restrict__ conv_w,
    const float* __restrict__ conv_b, const float* __restrict__ pe_g,
    const float* __restrict__ pe_b, const float* __restrict__ cls_tok,
    const float* __restrict__ pos, float* __restrict__ t)
{
    __shared__ float patch[48];
    __shared__ float red[192];
    int blk = blockIdx.x;
    int b = blk / 65, n = blk % 65;
    int tid = threadIdx.x;
    if (n == 0) {
        t[(size_t)b * 65 * DD + tid] = cls_tok[tid] + pos[tid];
        return;
    }
    int p = n - 1, gy = p / 8, gx = p % 8;
    if (tid < 48) {
        int c = tid / 16, iy = (tid % 16) / 4, ix = tid % 4;
        patch[tid] = x[((size_t)b * 3 + c) * 1024 + (size_t)(gy * 4 + iy) * 32 + (gx * 4 + ix)];
    }
    __syncthreads();
    float s = conv_b[tid];
    const float* w = conv_w + (size_t)tid * 48;
    #pragma unroll
    for (int f = 0; f < 48; f++) s += patch[f] * w[f];
    float mean = blk_sum_192(s, red) * (1.0f / 192.0f);
    float d = s - mean;
    float var = blk_sum_192(d * d, red) * (1.0f / 192.0f);
    float o = d * rsqrtf(var + 1e-5f) * pe_g[tid] + pe_b[tid];
    t[((size_t)b * 65 + n) * DD + tid] = o + pos[(size_t)n * DD + tid];
}

// ---------------- LayerNorm rows ----------------
// grid = nrows blocks, 192 threads; in row r at in + r*in_stride, out compact [r*192]
__global__ __launch_bounds__(192) void ln_kernel(
    const float* __restrict__ in, float* __restrict__ out,
    const float* __restrict__ g, const float* __restrict__ bb, long in_stride)
{
    __shared__ float red[192];
    int r = blockIdx.x, tid = threadIdx.x;
    float v = in[(size_t)r * in_stride + tid];
    float mean = blk_sum_192(v, red) * (1.0f / 192.0f);
    float d = v - mean;
    float var = blk_sum_192(d * d, red) * (1.0f / 192.0f);
    out[(size_t)r * DD + tid] = d * rsqrtf(var + 1e-5f) * g[tid] + bb[tid];
}

// ---------------- generic tiled GEMM: C[M,N] = A[M,K] @ W[N,K]^T ----------------
// MODE 0: C = acc + bias            (C stride = N)
// MODE 1: C = gelu(acc + bias)      (C stride = N)
// MODE 2: t[r*192+n] += scale[0] * (acc + bias)                 (N == 192)
// MODE 3: t[r*192+n] += scale[0] * gw[r*4+eidx] * (acc + bias)  (N == 192)
template <int MODE>
__global__ __launch_bounds__(256) void gemm_kernel(
    const float* __restrict__ A, const float* __restrict__ W,
    const float* __restrict__ bias, float* __restrict__ C,
    int Nn, int K,
    const float* __restrict__ scale, const float* __restrict__ gw, int eidx)
{
    constexpr int BM = 64, BN = 64, BK = 16, LDP = 68;
    __shared__ float As[BK][LDP];
    __shared__ float Bs[BK][LDP];
    int tid = threadIdx.x;
    int tx = tid & 15, ty = tid >> 4;
    int m0 = blockIdx.x * BM, n0 = blockIdx.y * BN;

    float acc[4][4] = {};
    for (int k0 = 0; k0 < K; k0 += BK) {
        #pragma unroll
        for (int i = 0; i < 4; i++) {
            int idx = tid + i * 256;
            int r = idx >> 4, c = idx & 15;
            As[c][r] = A[(size_t)(m0 + r) * K + k0 + c];
            Bs[c][r] = W[(size_t)(n0 + r) * K + k0 + c];
        }
        __syncthreads();
        #pragma unroll
        for (int kk = 0; kk < BK; kk++) {
            float a4[4], b4[4];
            #pragma unroll
            for (int i = 0; i < 4; i++) a4[i] = As[kk][ty * 4 + i];
            #pragma unroll
            for (int j = 0; j < 4; j++) b4[j] = Bs[kk][tx * 4 + j];
            #pragma unroll
            for (int i = 0; i < 4; i++)
                #pragma unroll
                for (int j = 0; j < 4; j++)
                    acc[i][j] += a4[i] * b4[j];
        }
        __syncthreads();
    }

    #pragma unroll
    for (int i = 0; i < 4; i++) {
        int r = m0 + ty * 4 + i;
        #pragma unroll
        for (int j = 0; j < 4; j++) {
            int n = n0 + tx * 4 + j;
            float v = acc[i][j] + (bias ? bias[n] : 0.0f);
            if (MODE == 0) {
                C[(size_t)r * Nn + n] = v;
            } else if (MODE == 1) {
                C[(size_t)r * Nn + n] = gelu_f(v);
            } else if (MODE == 2) {
                C[(size_t)r * DD + n] += scale[0] * v;
            } else {
                C[(size_t)r * DD + n] += scale[0] * gw[(size_t)r * 4 + eidx] * v;
            }
        }
    }
}

// ---------------- banded attention: grid = B*H blocks, 256 threads ----------------
__global__ __launch_bounds__(256) void attn_kernel(
    const float* __restrict__ qkv, const float* __restrict__ temp,
    float* __restrict__ o)
{
    __shared__ float q[65][64], k[65][64], v[65][64];
    __shared__ float p[65][8];
    int bh = blockIdx.x;
    int b = bh / 3, h = bh % 3;
    int tid = threadIdx.x;
    float coef = 0.125f / temp[h];
    const float* base = qkv + (size_t)b * 65 * 576 + h * 64;
    for (int idx = tid; idx < 65 * 64; idx += 256) {
        int i = idx >> 6, d = idx & 63;
        q[i][d] = base[(size_t)i * 576 + d];
        k[i][d] = base[(size_t)i * 576 + 192 + d];
        v[i][d] = base[(size_t)i * 576 + 384 + d];
    }
    __syncthreads();
    if (tid < 65) {
        int i = tid;
        float sc[7];
        float mx = -1e30f;
        #pragma unroll
        for (int jo = 0; jo < 7; jo++) {
            int j = i - 3 + jo;
            if (j >= 0 && j < 65) {
                float s = 0.f;
                #pragma unroll
                for (int d = 0; d < 64; d++) s += q[i][d] * k[j][d];
                sc[jo] = s * coef;
                mx = fmaxf(mx, sc[jo]);
            } else sc[jo] = -1e30f;
        }
        float sum = 0.f;
        #pragma unroll
        for (int jo = 0; jo < 7; jo++) {
            float e = expf(sc[jo] - mx);
            p[i][jo] = e;
            sum += e;
        }
        float inv = 1.0f / sum;
        #pragma unroll
        for (int jo = 0; jo < 7; jo++) p[i][jo] *= inv;
    }
    __syncthreads();
    for (int idx = tid; idx < 65 * 64; idx += 256) {
        int i = idx >> 6, d = idx & 63;
        float s = 0.f;
        #pragma unroll
        for (int jo = 0; jo < 7; jo++) {
            int j = i - 3 + jo;
            if (j >= 0 && j < 65) s += p[i][jo] * v[j][d];
        }
        o[((size_t)b * 65 + i) * DD + h * 64 + d] = s;
    }
}

// ---------------- gate: softmax(E=4) + top2 -> per-expert weights ----------------
__global__ __launch_bounds__(256) void gate_kernel(
    const float* __restrict__ y, const float* __restrict__ gwm,
    const float* __restrict__ gb, float* __restrict__ gw_out, int rows)
{
    int r = blockIdx.x * 256 + threadIdx.x;
    if (r >= rows) return;
    const float* yr = y + (size_t)r * DD;
    float g[4];
    #pragma unroll
    for (int e = 0; e < 4; e++) {
        float s = gb[e];
        const float* w = gwm + (size_t)e * DD;
        for (int kk = 0; kk < DD; kk++) s += yr[kk] * w[kk];
        g[e] = s;
    }
    float mx = fmaxf(fmaxf(g[0], g[1]), fmaxf(g[2], g[3]));
    float ex[4];
    #pragma unroll
    for (int e = 0; e < 4; e++) ex[e] = expf(g[e] - mx);
    int i0 = 0;
    #pragma unroll
    for (int e = 1; e < 4; e++) if (ex[e] > ex[i0]) i0 = e;
    int i1 = (i0 == 0) ? 1 : 0;
    #pragma unroll
    for (int e = 0; e < 4; e++) if (e != i0 && ex[e] > ex[i1]) i1 = e;
    float denom = ex[i0] + ex[i1];
    float w0 = ex[i0] / denom, w1 = ex[i1] / denom;
    float out[4] = {0.f, 0.f, 0.f, 0.f};
    out[i0] = w0; out[i1] = w1;
    #pragma unroll
    for (int e = 0; e < 4; e++) gw_out[(size_t)r * 4 + e] = out[e];
}

// ---------------- hyper head: grid = B blocks, 128 threads ----------------
__global__ __launch_bounds__(128) void head_kernel(
    const float* __restrict__ cls, const float* __restrict__ hc_w,
    const float* __restrict__ hc_b, const float* __restrict__ head_w,
    const float* __restrict__ head_b, float* __restrict__ out)
{
    __shared__ float c[192];
    __shared__ float hh[384];
    int b = blockIdx.x, tid = threadIdx.x;
    for (int i = tid; i < 192; i += 128) c[i] = cls[(size_t)b * 192 + i];
    __syncthreads();
    for (int i = tid; i < 384; i += 128) {
        int k = i / 96, o = i % 96;
        float s = hc_b[i];
        #pragma unroll
        for (int j = 0; j < 4; j++) {
            int pp = (k - j + 4) & 3;
            const float* w = hc_w + ((size_t)pp * 96 + o) * 48;
            const float* xv = c + j * 48;
            #pragma unroll
            for (int cc = 0; cc < 48; cc++) s += xv[cc] * w[cc];
        }
        hh[i] = gelu_f(s);
    }
    __syncthreads();
    for (int i = tid; i < 100; i += 128) {
        float s = head_b[i];
        const float* w = head_w + (size_t)i * 384;
        for (int kk = 0; kk < 384; kk++) s += hh[kk] * w[kk];
        out[(size_t)b * 100 + i] = s;
    }
}

extern "C" void kernel_launch(void* const* d_in, const int* in_sizes, int n_in,
                              void* d_out, int out_size, void* d_ws, size_t ws_size,
                              hipStream_t stream)
{
    const float* x        = (const float*)d_in[0];
    const float* conv_w   = (const float*)d_in[1];
    const float* conv_b   = (const float*)d_in[2];
    const float* pe_g     = (const float*)d_in[3];
    const float* pe_b     = (const float*)d_in[4];
    const float* cls_tok  = (const float*)d_in[5];
    const float* pos      = (const float*)d_in[6];
    const float* n1_g     = (const float*)d_in[7];
    const float* n1_b     = (const float*)d_in[8];
    const float* qkv_w    = (const float*)d_in[9];
    const float* temp     = (const float*)d_in[10];
    const float* proj_w   = (const float*)d_in[11];
    const float* proj_b   = (const float*)d_in[12];
    const float* n2_g     = (const float*)d_in[13];
    const float* n2_b     = (const float*)d_in[14];
    const float* gate_w   = (const float*)d_in[15];
    const float* gate_b   = (const float*)d_in[16];
    const float* e_w1     = (const float*)d_in[17];
    const float* e_b1     = (const float*)d_in[18];
    const float* e_w2     = (const float*)d_in[19];
    const float* e_b2     = (const float*)d_in[20];
    const float* attn_sc  = (const float*)d_in[21];
    const float* mlp_sc   = (const float*)d_in[22];
    const float* norm_g   = (const float*)d_in[23];
    const float* norm_b   = (const float*)d_in[24];
    const float* hc_w     = (const float*)d_in[25];
    const float* hc_b     = (const float*)d_in[26];
    const float* head_w   = (const float*)d_in[27];
    const float* head_b   = (const float*)d_in[28];

    float* ws   = (float*)d_ws;
    float* t    = ws;                              // 8320*192
    float* y    = t + (size_t)ROWS * DD;           // 8320*192
    float* qkvb = y + (size_t)ROWS * DD;           // 8320*576
    float* ob   = qkvb + (size_t)ROWS * 576;       // 8320*192
    float* gw   = ob + (size_t)ROWS * DD;          // 8320*4
    float* hb   = qkvb;                            // alias: expert hidden 8320*384 fits in qkv buffer

    embed_kernel<<<128 * 65, 192, 0, stream>>>(x, conv_w, conv_b, pe_g, pe_b, cls_tok, pos, t);

    for (int l = 0; l < 12; l++) {
        ln_kernel<<<ROWS, 192, 0, stream>>>(t, y, n1_g + l * DD, n1_b + l * DD, DD);
        gemm_kernel<0><<<dim3(130, 9), 256, 0, stream>>>(
            y, qkv_w + (size_t)l * 576 * DD, nullptr, qkvb, 576, DD, nullptr, nullptr, 0);
        attn_kernel<<<128 * 3, 256, 0, stream>>>(qkvb, temp + l * 3, ob);
        gemm_kernel<2><<<dim3(130, 3), 256, 0, stream>>>(
            ob, proj_w + (size_t)l * DD * DD, proj_b + l * DD, t, DD, DD, attn_sc + l, nullptr, 0);
        ln_kernel<<<ROWS, 192, 0, stream>>>(t, y, n2_g + l * DD, n2_b + l * DD, DD);
        gate_kernel<<<(ROWS + 255) / 256, 256, 0, stream>>>(
            y, gate_w + (size_t)l * 4 * DD, gate_b + l * 4, gw, ROWS);
        for (int e = 0; e < 4; e++) {
            int le = l * 4 + e;
            gemm_kernel<1><<<dim3(130, 6), 256, 0, stream>>>(
                y, e_w1 + (size_t)le * 384 * DD, e_b1 + (size_t)le * 384, hb, 384, DD,
                nullptr, nullptr, 0);
            gemm_kernel<3><<<dim3(130, 3), 256, 0, stream>>>(
                hb, e_w2 + (size_t)le * DD * 384, e_b2 + (size_t)le * DD, t, DD, 384,
                mlp_sc + l, gw, e);
        }
    }

    // final LN on cls rows only (row stride 65*192), then hyper head
    ln_kernel<<<128, 192, 0, stream>>>(t, y, norm_g, norm_b, (long)65 * DD);
    head_kernel<<<128, 128, 0, stream>>>(y, hc_w, hc_b, head_w, head_b, (float*)d_out);
}

// Round 3
// 2083.578 us; speedup vs baseline: 2.1233x; 2.1233x over previous
//
#include <hip/hip_runtime.h>
#include <cmath>

// Shapes: B=128, D=192, DEPTH=12, H=3(hd=64), E=4, N=65(tokens), NC=100, WIN_HALF=3
#define ROWS 8320
#define DD   192

typedef __attribute__((ext_vector_type(8))) short bhalf8;
typedef __attribute__((ext_vector_type(4))) float floatx4;

#define GLD16(gp, lp) __builtin_amdgcn_global_load_lds( \
    (const __attribute__((address_space(1))) void*)(gp), \
    (__attribute__((address_space(3))) void*)(lp), 16, 0, 0)

__device__ __forceinline__ float gelu_f(float x) {
    return 0.5f * x * (1.0f + erff(x * 0.70710678118654752440f));
}
__device__ __forceinline__ ushort f2b(float f) {
    unsigned u = __float_as_uint(f);
    unsigned r = (u + 0x7FFFu + ((u >> 16) & 1u)) >> 16;
    return (ushort)r;
}
__device__ __forceinline__ float b2f(ushort u) {
    return __uint_as_float(((unsigned)u) << 16);
}

// block-wide sum for blockDim.x == 192
__device__ __forceinline__ float blk_sum_192(float v, float* sbuf) {
    int tid = threadIdx.x;
    sbuf[tid] = v;
    __syncthreads();
    for (int off = 96; off >= 3; off >>= 1) {
        if (tid < off) sbuf[tid] += sbuf[tid + off];
        __syncthreads();
    }
    float r = sbuf[0] + sbuf[1] + sbuf[2];
    __syncthreads();
    return r;
}

// ---------------- weight split-convert: flat [rows*K] fp32 -> [pair][hi8|lo8] ----------------
// one thread per 8-elem pair
__global__ __launch_bounds__(256) void cvt_split_kernel(
    const float* __restrict__ s, ushort* __restrict__ d, long npairs)
{
    long i = (long)blockIdx.x * 256 + threadIdx.x;
    if (i >= npairs) return;
    const float* sp = s + i * 8;
    ushort* dp = d + i * 16;
    #pragma unroll
    for (int j = 0; j < 8; j++) {
        float v = sp[j];
        ushort hi = f2b(v);
        float lo = v - b2f(hi);
        dp[j] = hi;
        dp[8 + j] = f2b(lo);
    }
}

// e_w2 (12,4,192,384) -> split-pair layout [l][n][K'=1536] with col = e*384+k
__global__ __launch_bounds__(256) void permw2_kernel(
    const float* __restrict__ s, ushort* __restrict__ d)
{
    long i = (long)blockIdx.x * 256 + threadIdx.x;   // (l, n, p), p in 0..191
    if (i >= (long)12 * 192 * 192) return;
    int l = (int)(i / (192 * 192));
    int rem = (int)(i % (192 * 192));
    int n = rem / 192, p = rem % 192;
    int c0 = p * 8;
    int e = c0 / 384, k0 = c0 % 384;
    const float* sp = s + (((size_t)l * 4 + e) * 192 + n) * 384 + k0;
    ushort* dp = d + i * 16;
    #pragma unroll
    for (int j = 0; j < 8; j++) {
        float v = sp[j];
        ushort hi = f2b(v);
        float lo = v - b2f(hi);
        dp[j] = hi;
        dp[8 + j] = f2b(lo);
    }
}

// ---------------- patch embed + LN + cls + pos (fp32) ----------------
__global__ __launch_bounds__(192) void embed_kernel(
    const float* __restrict__ x, const float* __restrict__ conv_w,
    const float* __restrict__ conv_b, const float* __restrict__ pe_g,
    const float* __restrict__ pe_b, const float* __restrict__ cls_tok,
    const float* __restrict__ pos, float* __restrict__ t)
{
    __shared__ float patch[48];
    __shared__ float red[192];
    int blk = blockIdx.x;
    int b = blk / 65, n = blk % 65;
    int tid = threadIdx.x;
    if (n == 0) {
        t[(size_t)b * 65 * DD + tid] = cls_tok[tid] + pos[tid];
        return;
    }
    int p = n - 1, gy = p / 8, gx = p % 8;
    if (tid < 48) {
        int c = tid / 16, iy = (tid % 16) / 4, ix = tid % 4;
        patch[tid] = x[((size_t)b * 3 + c) * 1024 + (size_t)(gy * 4 + iy) * 32 + (gx * 4 + ix)];
    }
    __syncthreads();
    float s = conv_b[tid];
    const float* w = conv_w + (size_t)tid * 48;
    #pragma unroll
    for (int f = 0; f < 48; f++) s += patch[f] * w[f];
    float mean = blk_sum_192(s, red) * (1.0f / 192.0f);
    float d = s - mean;
    float var = blk_sum_192(d * d, red) * (1.0f / 192.0f);
    float o = d * rsqrtf(var + 1e-5f) * pe_g[tid] + pe_b[tid];
    t[((size_t)b * 65 + n) * DD + tid] = o + pos[(size_t)n * DD + tid];
}

// ---------------- LayerNorm: fp32 in (strided); fp32 out (opt) + split-pair out (opt) ----------------
__global__ __launch_bounds__(192) void ln_kernel(
    const float* __restrict__ in, float* __restrict__ yf, ushort* __restrict__ ysp,
    const float* __restrict__ g, const float* __restrict__ bb, long in_stride)
{
    __shared__ float red[192];
    int r = blockIdx.x, tid = threadIdx.x;
    float v = in[(size_t)r * in_stride + tid];
    float mean = blk_sum_192(v, red) * (1.0f / 192.0f);
    float d = v - mean;
    float var = blk_sum_192(d * d, red) * (1.0f / 192.0f);
    float o = d * rsqrtf(var + 1e-5f) * g[tid] + bb[tid];
    if (yf) yf[(size_t)r * DD + tid] = o;
    if (ysp) {
        int p = tid >> 3, pos = tid & 7;
        ushort hi = f2b(o);
        ysp[(size_t)r * 384 + p * 16 + pos] = hi;
        ysp[(size_t)r * 384 + p * 16 + 8 + pos] = f2b(o - b2f(hi));
    }
}

// ---------------- split-bf16 MFMA GEMM: C[M,N] = A[M,K] @ W[N,K]^T ----------------
// A,W in split-pair layout: row stride = K*2 ushorts, pair p at [p*16 .. p*16+15]
// = hi8 | lo8. acc = Ah*Wh + Ah*Wl + Al*Wh  (~fp32 precision).
// BM=BN=64, 256 thr = 4 waves each 32x32 via 2x2 of 16x16x32 MFMA. K staged 96/iter.
// LDS chunks XOR-swizzled by row&7 for conflict-free ds_read_b128.
// MODE 0: qkv  -> outF fp32 [M][Nn]
// MODE 1: ew1  -> outS split-pair (row stride 1536*2) = gw[r,n/384]*gelu(acc+bias[n])
// MODE 2: proj -> t[r*192+n] += scale[0]*(acc + bias[n])
// MODE 3: ew2  -> t[r*192+n] += scale[0]*(acc + sum_e gw[r,e]*bias[e*192+n])
template <int MODE>
__global__ __launch_bounds__(256) void mfma_gemm(
    const ushort* __restrict__ A, const ushort* __restrict__ W,
    int Nn, int Ktot,
    float* __restrict__ outF, ushort* __restrict__ outS, float* __restrict__ t,
    const float* __restrict__ bias, const float* __restrict__ scale,
    const float* __restrict__ gw)
{
    __shared__ __align__(16) ushort As[64 * 192];   // 64 rows x 24 chunks x 8
    __shared__ __align__(16) ushort Ws[64 * 192];
    const int tid = threadIdx.x;
    const int lane = tid & 63, wave = tid >> 6;
    const int m0 = blockIdx.x * 64, n0 = blockIdx.y * 64;
    const int wm = (wave & 1) * 32, wn = (wave >> 1) * 32;
    const int lr = lane & 15, quad = lane >> 4;

    floatx4 zero = {0.f, 0.f, 0.f, 0.f};
    floatx4 acc[2][2];
    acc[0][0] = zero; acc[0][1] = zero; acc[1][0] = zero; acc[1][1] = zero;

    const int nstage = Ktot / 96;
    const size_t rstride = (size_t)Ktot * 2;   // ushorts per row

    for (int st = 0; st < nstage; st++) {
        #pragma unroll
        for (int j = 0; j < 6; j++) {
            int sidx = (wave * 6 + j) * 64 + lane;        // 0..1535
            int row = sidx / 24, c = sidx % 24;
            int gc = st * 24 + (c ^ (row & 7));
            GLD16(A + (size_t)(m0 + row) * rstride + gc * 8,
                  (char*)As + (size_t)(wave * 6 + j) * 1024);
            GLD16(W + (size_t)(n0 + row) * rstride + gc * 8,
                  (char*)Ws + (size_t)(wave * 6 + j) * 1024);
        }
        __syncthreads();
        #pragma unroll
        for (int m = 0; m < 3; m++) {
            int p = m * 4 + quad;                          // pair 0..11
            bhalf8 ah[2], al[2], wh[2], wl[2];
            #pragma unroll
            for (int ti = 0; ti < 2; ti++) {
                int row = wm + ti * 16 + lr;
                ah[ti] = *(const bhalf8*)(As + (row * 24 + ((2 * p) ^ (row & 7))) * 8);
                al[ti] = *(const bhalf8*)(As + (row * 24 + ((2 * p + 1) ^ (row & 7))) * 8);
                int col = wn + ti * 16 + lr;
                wh[ti] = *(const bhalf8*)(Ws + (col * 24 + ((2 * p) ^ (col & 7))) * 8);
                wl[ti] = *(const bhalf8*)(Ws + (col * 24 + ((2 * p + 1) ^ (col & 7))) * 8);
            }
            #pragma unroll
            for (int ti = 0; ti < 2; ti++)
                #pragma unroll
                for (int tj = 0; tj < 2; tj++) {
                    acc[ti][tj] = __builtin_amdgcn_mfma_f32_16x16x32_bf16(
                        ah[ti], wh[tj], acc[ti][tj], 0, 0, 0);
                    acc[ti][tj] = __builtin_amdgcn_mfma_f32_16x16x32_bf16(
                        ah[ti], wl[tj], acc[ti][tj], 0, 0, 0);
                    acc[ti][tj] = __builtin_amdgcn_mfma_f32_16x16x32_bf16(
                        al[ti], wh[tj], acc[ti][tj], 0, 0, 0);
                }
        }
        __syncthreads();
    }

    float sc = (MODE == 2 || MODE == 3) ? scale[0] : 0.f;
    #pragma unroll
    for (int ti = 0; ti < 2; ti++)
        #pragma unroll
        for (int tj = 0; tj < 2; tj++)
            #pragma unroll
            for (int r = 0; r < 4; r++) {
                int grow = m0 + wm + ti * 16 + quad * 4 + r;
                int gcol = n0 + wn + tj * 16 + lr;
                float v = acc[ti][tj][r];
                if (MODE == 0) {
                    outF[(size_t)grow * Nn + gcol] = v;
                } else if (MODE == 1) {
                    v = gelu_f(v + bias[gcol]);
                    v *= gw[grow * 4 + (gcol / 384)];
                    int p = gcol >> 3, pos = gcol & 7;
                    ushort hi = f2b(v);
                    outS[(size_t)grow * 3072 + p * 16 + pos] = hi;
                    outS[(size_t)grow * 3072 + p * 16 + 8 + pos] = f2b(v - b2f(hi));
                } else if (MODE == 2) {
                    t[(size_t)grow * DD + gcol] += sc * (v + bias[gcol]);
                } else {
                    float bb = gw[grow * 4 + 0] * bias[gcol]
                             + gw[grow * 4 + 1] * bias[192 + gcol]
                             + gw[grow * 4 + 2] * bias[384 + gcol]
                             + gw[grow * 4 + 3] * bias[576 + gcol];
                    t[(size_t)grow * DD + gcol] += sc * (v + bb);
                }
            }
}

// ---------------- banded attention: fp32 qkv in, split-pair o out ----------------
__global__ __launch_bounds__(256) void attn_kernel(
    const float* __restrict__ qkv, const float* __restrict__ temp,
    ushort* __restrict__ o)
{
    __shared__ float q[65][64], k[65][64], v[65][64];
    __shared__ float p[65][8];
    int bh = blockIdx.x;
    int b = bh / 3, h = bh % 3;
    int tid = threadIdx.x;
    float coef = 0.125f / temp[h];
    const float* base = qkv + (size_t)b * 65 * 576 + h * 64;
    for (int idx = tid; idx < 65 * 64; idx += 256) {
        int i = idx >> 6, d = idx & 63;
        q[i][d] = base[(size_t)i * 576 + d];
        k[i][d] = base[(size_t)i * 576 + 192 + d];
        v[i][d] = base[(size_t)i * 576 + 384 + d];
    }
    __syncthreads();
    if (tid < 65) {
        int i = tid;
        float sc[7];
        float mx = -1e30f;
        #pragma unroll
        for (int jo = 0; jo < 7; jo++) {
            int j = i - 3 + jo;
            if (j >= 0 && j < 65) {
                float s = 0.f;
                #pragma unroll
                for (int d = 0; d < 64; d++) s += q[i][d] * k[j][d];
                sc[jo] = s * coef;
                mx = fmaxf(mx, sc[jo]);
            } else sc[jo] = -1e30f;
        }
        float sum = 0.f;
        #pragma unroll
        for (int jo = 0; jo < 7; jo++) {
            float e = expf(sc[jo] - mx);
            p[i][jo] = e;
            sum += e;
        }
        float inv = 1.0f / sum;
        #pragma unroll
        for (int jo = 0; jo < 7; jo++) p[i][jo] *= inv;
    }
    __syncthreads();
    for (int idx = tid; idx < 65 * 64; idx += 256) {
        int i = idx >> 6, d = idx & 63;
        float s = 0.f;
        #pragma unroll
        for (int jo = 0; jo < 7; jo++) {
            int j = i - 3 + jo;
            if (j >= 0 && j < 65) s += p[i][jo] * v[j][d];
        }
        int col = h * 64 + d;
        int pp = col >> 3, pos = col & 7;
        size_t rb = ((size_t)b * 65 + i) * 384;
        ushort hi = f2b(s);
        o[rb + pp * 16 + pos] = hi;
        o[rb + pp * 16 + 8 + pos] = f2b(s - b2f(hi));
    }
}

// ---------------- gate: softmax(E=4) + top2 (fp32) ----------------
__global__ __launch_bounds__(256) void gate_kernel(
    const float* __restrict__ y, const float* __restrict__ gwm,
    const float* __restrict__ gb, float* __restrict__ gw_out, int rows)
{
    int r = blockIdx.x * 256 + threadIdx.x;
    if (r >= rows) return;
    const float* yr = y + (size_t)r * DD;
    float g[4];
    #pragma unroll
    for (int e = 0; e < 4; e++) {
        float s = gb[e];
        const float* w = gwm + (size_t)e * DD;
        for (int kk = 0; kk < DD; kk++) s += yr[kk] * w[kk];
        g[e] = s;
    }
    float mx = fmaxf(fmaxf(g[0], g[1]), fmaxf(g[2], g[3]));
    float ex[4];
    #pragma unroll
    for (int e = 0; e < 4; e++) ex[e] = expf(g[e] - mx);
    int i0 = 0;
    #pragma unroll
    for (int e = 1; e < 4; e++) if (ex[e] > ex[i0]) i0 = e;
    int i1 = (i0 == 0) ? 1 : 0;
    #pragma unroll
    for (int e = 0; e < 4; e++) if (e != i0 && ex[e] > ex[i1]) i1 = e;
    float denom = ex[i0] + ex[i1];
    float out[4] = {0.f, 0.f, 0.f, 0.f};
    out[i0] = ex[i0] / denom; out[i1] = ex[i1] / denom;
    #pragma unroll
    for (int e = 0; e < 4; e++) gw_out[(size_t)r * 4 + e] = out[e];
}

// ---------------- hyper head (fp32) ----------------
__global__ __launch_bounds__(128) void head_kernel(
    const float* __restrict__ cls, const float* __restrict__ hc_w,
    const float* __restrict__ hc_b, const float* __restrict__ head_w,
    const float* __restrict__ head_b, float* __restrict__ out)
{
    __shared__ float c[192];
    __shared__ float hh[384];
    int b = blockIdx.x, tid = threadIdx.x;
    for (int i = tid; i < 192; i += 128) c[i] = cls[(size_t)b * 192 + i];
    __syncthreads();
    for (int i = tid; i < 384; i += 128) {
        int k = i / 96, o = i % 96;
        float s = hc_b[i];
        #pragma unroll
        for (int j = 0; j < 4; j++) {
            int pp = (k - j + 4) & 3;
            const float* w = hc_w + ((size_t)pp * 96 + o) * 48;
            const float* xv = c + j * 48;
            #pragma unroll
            for (int cc = 0; cc < 48; cc++) s += xv[cc] * w[cc];
        }
        hh[i] = gelu_f(s);
    }
    __syncthreads();
    for (int i = tid; i < 100; i += 128) {
        float s = head_b[i];
        const float* w = head_w + (size_t)i * 384;
        for (int kk = 0; kk < 384; kk++) s += hh[kk] * w[kk];
        out[(size_t)b * 100 + i] = s;
    }
}

extern "C" void kernel_launch(void* const* d_in, const int* in_sizes, int n_in,
                              void* d_out, int out_size, void* d_ws, size_t ws_size,
                              hipStream_t stream)
{
    const float* x        = (const float*)d_in[0];
    const float* conv_w   = (const float*)d_in[1];
    const float* conv_b   = (const float*)d_in[2];
    const float* pe_g     = (const float*)d_in[3];
    const float* pe_b     = (const float*)d_in[4];
    const float* cls_tok  = (const float*)d_in[5];
    const float* pos      = (const float*)d_in[6];
    const float* n1_g     = (const float*)d_in[7];
    const float* n1_b     = (const float*)d_in[8];
    const float* qkv_w    = (const float*)d_in[9];
    const float* temp     = (const float*)d_in[10];
    const float* proj_w   = (const float*)d_in[11];
    const float* proj_b   = (const float*)d_in[12];
    const float* n2_g     = (const float*)d_in[13];
    const float* n2_b     = (const float*)d_in[14];
    const float* gate_w   = (const float*)d_in[15];
    const float* gate_b   = (const float*)d_in[16];
    const float* e_w1     = (const float*)d_in[17];
    const float* e_b1     = (const float*)d_in[18];
    const float* e_w2     = (const float*)d_in[19];
    const float* e_b2     = (const float*)d_in[20];
    const float* attn_sc  = (const float*)d_in[21];
    const float* mlp_sc   = (const float*)d_in[22];
    const float* norm_g   = (const float*)d_in[23];
    const float* norm_b   = (const float*)d_in[24];
    const float* hc_w     = (const float*)d_in[25];
    const float* hc_b     = (const float*)d_in[26];
    const float* head_w   = (const float*)d_in[27];
    const float* head_b   = (const float*)d_in[28];

    // ---- ws layout (all blocks multiples of 16B) ----
    char* base = (char*)d_ws;
    float*  t    = (float*)base;   base += (size_t)ROWS * DD * 4;        // 6.39MB
    float*  y    = (float*)base;   base += (size_t)ROWS * DD * 4;        // 6.39MB
    float*  gw   = (float*)base;   base += (size_t)ROWS * 4 * 4;         // 133KB
    ushort* ysp  = (ushort*)base;  base += (size_t)ROWS * 384 * 2;       // 6.39MB split y
    ushort* osp  = (ushort*)base;  base += (size_t)ROWS * 384 * 2;       // 6.39MB split attn-out
    char*   big  = base;           base += (size_t)ROWS * 3072 * 2;      // 51.1MB
    float*  qkvf = (float*)big;            // [8320][576] fp32 (first 19.2MB)
    ushort* hsp  = (ushort*)big;           // [8320][1536] split (full region); aliases qkvf (disjoint in time)
    ushort* qkvw_sp = (ushort*)base; base += (size_t)12 * 576 * 384 * 2;   // 5.3MB
    ushort* projw_sp = (ushort*)base; base += (size_t)12 * 192 * 384 * 2;  // 1.8MB
    ushort* ew1_sp  = (ushort*)base; base += (size_t)12 * 1536 * 384 * 2;  // 14.2MB
    ushort* ew2_sp  = (ushort*)base; base += (size_t)12 * 192 * 3072 * 2;  // 14.2MB

    // ---- weight split-conversion ----
    {
        long np = (long)12 * 576 * 192 / 8;
        cvt_split_kernel<<<(int)((np + 255) / 256), 256, 0, stream>>>(qkv_w, qkvw_sp, np);
        np = (long)12 * 192 * 192 / 8;
        cvt_split_kernel<<<(int)((np + 255) / 256), 256, 0, stream>>>(proj_w, projw_sp, np);
        np = (long)12 * 1536 * 192 / 8;
        cvt_split_kernel<<<(int)((np + 255) / 256), 256, 0, stream>>>(e_w1, ew1_sp, np);
        long n = (long)12 * 192 * 192;   // (l,n,p) tasks, p in 0..191
        permw2_kernel<<<(int)((n + 255) / 256), 256, 0, stream>>>(e_w2, ew2_sp);
    }

    embed_kernel<<<128 * 65, 192, 0, stream>>>(x, conv_w, conv_b, pe_g, pe_b, cls_tok, pos, t);

    for (int l = 0; l < 12; l++) {
        ln_kernel<<<ROWS, 192, 0, stream>>>(t, nullptr, ysp, n1_g + l * DD, n1_b + l * DD, DD);
        mfma_gemm<0><<<dim3(130, 9), 256, 0, stream>>>(
            ysp, qkvw_sp + (size_t)l * 576 * 384, 576, 192,
            qkvf, nullptr, nullptr, nullptr, nullptr, nullptr);
        attn_kernel<<<128 * 3, 256, 0, stream>>>(qkvf, temp + l * 3, osp);
        mfma_gemm<2><<<dim3(130, 3), 256, 0, stream>>>(
            osp, projw_sp + (size_t)l * 192 * 384, 192, 192,
            nullptr, nullptr, t, proj_b + l * DD, attn_sc + l, nullptr);
        ln_kernel<<<ROWS, 192, 0, stream>>>(t, y, ysp, n2_g + l * DD, n2_b + l * DD, DD);
        gate_kernel<<<(ROWS + 255) / 256, 256, 0, stream>>>(
            y, gate_w + (size_t)l * 4 * DD, gate_b + l * 4, gw, ROWS);
        mfma_gemm<1><<<dim3(130, 24), 256, 0, stream>>>(
            ysp, ew1_sp + (size_t)l * 1536 * 384, 1536, 192,
            nullptr, hsp, nullptr, e_b1 + (size_t)l * 1536, nullptr, gw);
        mfma_gemm<3><<<dim3(130, 3), 256, 0, stream>>>(
            hsp, ew2_sp + (size_t)l * 192 * 3072, 192, 1536,
            nullptr, nullptr, t, e_b2 + (size_t)l * 4 * 192, mlp_sc + l, gw);
    }

    ln_kernel<<<128, 192, 0, stream>>>(t, y, nullptr, norm_g, norm_b, (long)65 * DD);
    head_kernel<<<128, 128, 0, stream>>>(y, hc_w, hc_b, head_w, head_b, (float*)d_out);
}